// Round 1
// baseline (5479.012 us; speedup 1.0000x reference)
//
#include <hip/hip_runtime.h>

// ---------------------------------------------------------------------------
// XiRNN (peephole LSTM) on MI355X.  B=64, T=188, I=512, H=R=1024.
//   k_prep : fp32->bf16 conversion; W_rec split into bf16 hi+lo; zero flags.
//   k_px   : px[t][gate][j][b] = x[b,t,:]·W_ih[gate*H+j,:] + bias (MFMA GEMM)
//   k_scan : R8 redesign. The R7 kernel (256 CUs, 4 independent 64-CU groups)
//   was serialization-latency bound: 8.2us/step with MfmaUtil 6.6% (~400 cy of
//   MFMA per SIMD per step vs ~6000 cy step time; DVFS-throttled clocks).
//   R8: time-multiplex all 4 batch-group chains onto ONE 64-CU set. Each CU
//   owns 16 hidden cols for ALL 64 batch rows; slots cycle (g0,t)..(g3,t).
//   The 3-4 L3 round trips per group-step now hide under the other 3 groups'
//   compute:
//     - state loads for slot s+1 prefetched into a 2nd reg buffer during s;
//     - flag value for slot s+1 prefetched one slot earlier (spin only on miss);
//     - flag post for slot s-1 sits behind slot s's free vmcnt(0) drain;
//     - per-wave K=256 slice of ALL products -> 10 independent MFMA acc chains;
//     - W_rec lo-compensation tiles streamed from LDS (conflict-free b128),
//       freeing registers for the double-buffered state.
// ---------------------------------------------------------------------------

#define T_N 188
#define NSLOT (4 * T_N)

// ws byte offsets (256-aligned). Total = 132,648,960 B (~126.5 MiB).
#define WS_PX     0UL           // ushort[188*4096*64]   = 98,566,144 B
#define WS_XB     98566144UL    // ushort[64*188*512]    = 12,320,768 B
#define WS_WIHB   110886912UL   // ushort[4096*512]      =  4,194,304 B
#define WS_WCOMB  115081216UL   // ushort[6144*1024]     = 12,582,912 B
#define WS_HST    127664128UL   // ushort[2][64][1024]   =    262,144 B
#define WS_CST    127926272UL   // ushort[2][64][1024]   =    262,144 B
#define WS_FLAGS  128188416UL   // int[1024]             =      4,096 B
#define WS_WRECLO 128192512UL   // ushort[2048*1024]     =  4,194,304 B
#define WS_CSTLO  132386816UL   // ushort[2][64][1024]   =    262,144 B

typedef __attribute__((ext_vector_type(8))) short short8;
typedef __attribute__((ext_vector_type(4))) float f4;

__device__ __forceinline__ float b2f(unsigned short u) {
    union { unsigned int i; float f; } v; v.i = ((unsigned int)u) << 16; return v.f;
}
__device__ __forceinline__ unsigned short f2b(float f) {
    unsigned int u = __float_as_uint(f);
    return (unsigned short)((u + 0x7FFFu + ((u >> 16) & 1u)) >> 16);
}
__device__ __forceinline__ float sigf(float x) { return 1.0f / (1.0f + __expf(-x)); }
__device__ __forceinline__ float tanh_(float x) {
    float e = __expf(2.0f * x); return 1.0f - 2.0f / (e + 1.0f);
}
#define MFMA(a, b, c) __builtin_amdgcn_mfma_f32_16x16x32_bf16((a), (b), (c), 0, 0, 0)

// 16B state load through the device-coherent point (bypasses stale L1/L2)
__device__ __forceinline__ short8 ld_state(const unsigned short* p) {
    union { unsigned long long u[2]; short8 v; } r;
    r.u[0] = __hip_atomic_load((unsigned long long*)p,     __ATOMIC_RELAXED, __HIP_MEMORY_SCOPE_AGENT);
    r.u[1] = __hip_atomic_load((unsigned long long*)p + 1, __ATOMIC_RELAXED, __HIP_MEMORY_SCOPE_AGENT);
    return r.v;
}

__device__ __forceinline__ f4 px_init(const unsigned short* px, int t, int gate, int jg, int brow) {
    unsigned long long pv =
        *(const unsigned long long*)(px + ((long)(t * 4 + gate) * 1024 + jg) * 64 + brow);
    f4 r;
    r[0] = b2f((unsigned short)pv);
    r[1] = b2f((unsigned short)(pv >> 16));
    r[2] = b2f((unsigned short)(pv >> 32));
    r[3] = b2f((unsigned short)(pv >> 48));
    return r;
}

// ---------------------------------------------------------------------------
__global__ void k_prep(const float* __restrict__ x, const float* __restrict__ h0,
                       const float* __restrict__ c0, const float* __restrict__ wih,
                       const float* __restrict__ whh, const float* __restrict__ wrec,
                       unsigned short* __restrict__ xb, unsigned short* __restrict__ wihb,
                       unsigned short* __restrict__ wcomb, unsigned short* __restrict__ hst,
                       unsigned short* __restrict__ cst, unsigned short* __restrict__ wreclo,
                       unsigned short* __restrict__ cstlo, int* __restrict__ flags) {
    const long NX4 = 1540096, NWIH4 = 524288, NWHH4 = 1048576, NWREC4 = 524288, NH4 = 16384;
    const long total = NX4 + NWIH4 + NWHH4 + NWREC4 + NH4 + NH4;
    long gtid = (long)blockIdx.x * blockDim.x + threadIdx.x;
    for (long i = gtid; i < total; i += (long)gridDim.x * blockDim.x) {
        const float* src; unsigned short* dst; unsigned short* lo_dst = nullptr; long off = i;
        if (off < NX4)                   { src = x;    dst = xb; }
        else if ((off -= NX4) < NWIH4)   { src = wih;  dst = wihb; }
        else if ((off -= NWIH4) < NWHH4) { src = whh;  dst = wcomb; }
        else if ((off -= NWHH4) < NWREC4){ src = wrec; dst = wcomb + 4194304; lo_dst = wreclo; }
        else if ((off -= NWREC4) < NH4)  { src = h0;   dst = hst + 65536; }     // state slot 1
        else { off -= NH4;                 src = c0;   dst = cst + 65536; lo_dst = cstlo + 65536; }
        float4 v = ((const float4*)src)[off];
        unsigned short hx = f2b(v.x), hy = f2b(v.y), hz = f2b(v.z), hw = f2b(v.w);
        unsigned long long o = (unsigned long long)hx
            | ((unsigned long long)hy << 16)
            | ((unsigned long long)hz << 32)
            | ((unsigned long long)hw << 48);
        *(unsigned long long*)(dst + off * 4) = o;
        if (lo_dst) {
            unsigned long long l = (unsigned long long)f2b(v.x - b2f(hx))
                | ((unsigned long long)f2b(v.y - b2f(hy)) << 16)
                | ((unsigned long long)f2b(v.z - b2f(hz)) << 32)
                | ((unsigned long long)f2b(v.w - b2f(hw)) << 48);
            *(unsigned long long*)(lo_dst + off * 4) = l;
        }
    }
    if (gtid < 1024) flags[gtid] = 0;
}

// ---------------------------------------------------------------------------
// px GEMM: block = (t, 64-col slab), 4 waves, each wave one 16-col tile, M=64.
__global__ void __launch_bounds__(256) k_px(const unsigned short* __restrict__ xb,
                                            const unsigned short* __restrict__ wihb,
                                            const float* __restrict__ bias,
                                            unsigned short* __restrict__ px) {
    const int t = blockIdx.y;
    const int wv = threadIdx.x >> 6, lane = threadIdx.x & 63;
    const int col = lane & 15, quad = lane >> 4;
    const int n = blockIdx.x * 64 + wv * 16 + col;   // 0..4095 combined gate*H+j
    const float bn = bias[n];
    f4 acc[4];
#pragma unroll
    for (int mt = 0; mt < 4; ++mt) { acc[mt][0] = bn; acc[mt][1] = bn; acc[mt][2] = bn; acc[mt][3] = bn; }
    const unsigned short* bp = wihb + n * 512 + quad * 8;
#pragma unroll 4
    for (int kk = 0; kk < 16; ++kk) {
        short8 bf = *(const short8*)(bp + kk * 32);
#pragma unroll
        for (int mt = 0; mt < 4; ++mt) {
            const unsigned short* ap = xb + ((mt * 16 + col) * 188 + t) * 512 + kk * 32 + quad * 8;
            short8 af = *(const short8*)ap;
            acc[mt] = MFMA(af, bf, acc[mt]);
        }
    }
    const long pb = ((long)(t * 4 + (n >> 10)) * 1024 + (n & 1023)) * 64;
#pragma unroll
    for (int mt = 0; mt < 4; ++mt) {
        unsigned long long o = (unsigned long long)f2b(acc[mt][0])
            | ((unsigned long long)f2b(acc[mt][1]) << 16)
            | ((unsigned long long)f2b(acc[mt][2]) << 32)
            | ((unsigned long long)f2b(acc[mt][3]) << 48);
        *(unsigned long long*)(px + pb + mt * 16 + quad * 4) = o;
    }
}

// ---------------------------------------------------------------------------
// Persistent pipelined scan. 64 blocks (1/CU); cu = col-set (16 hidden cols).
// 4 waves = 4 K-slices of 256; each wave computes partials of ALL 6 products
// (4 gates from h@W_hh, 2 compensated peephole sums) for its K-slice.
// Slot s = (g = s&3, t = s>>2). State regs double-buffered (A/B alternate
// per slot); loop unrolled x4 so g, pre-parity, c-register are static.
//
// Slot order per wave:
//   px issue (wv0/wv1) -> MFMA (consumes prefetched state) -> px add ->
//   pre[] writes -> flag check slot s+1 (value prefetched at s-1; spin on
//   miss) -> vmcnt(0) (drains slot s-1 stores; ~free) -> prefetch state
//   s+1 + flag value s+2 -> barrier -> post flag for slot s-1 -> epilogue
//   (gates, c update, state + out stores).
__global__ void __launch_bounds__(256, 1) k_scan(
    const unsigned short* __restrict__ wcomb, const unsigned short* __restrict__ wreclo,
    const float* __restrict__ c0, const int* __restrict__ lengths,
    const unsigned short* __restrict__ px, unsigned short* __restrict__ hst,
    unsigned short* __restrict__ cst, unsigned short* __restrict__ cstlo,
    int* __restrict__ flags, float* __restrict__ out) {
    const int cu = blockIdx.x;                 // 0..63: column set
    const int jbase = cu * 16;
    const int tid = threadIdx.x, wv = tid >> 6, lane = tid & 63;
    const int kbase = wv * 256;                // per-wave K-slice
    const int col = lane & 15, quad = lane >> 4;

    __shared__ float pre[2][4][6][16][16];               // [ps][kq][tile][b][j] 48 KB
    __shared__ __align__(16) unsigned short wlo[4][2][8][512];  // W_rec lo slices 64 KB

    // ---- one-time: weights -> regs / LDS -------------------------------
    short8 wg[4][8];   // gate tiles (W_hh), this wave's K-slice
    short8 wh[2][8];   // peephole hi tiles (ri_hi, rf_hi)
#pragma unroll
    for (int g = 0; g < 4; ++g) {
        const unsigned short* src = wcomb + (long)(g * 1024 + jbase + col) * 1024 + kbase + quad * 8;
#pragma unroll
        for (int kk = 0; kk < 8; ++kk) wg[g][kk] = *(const short8*)(src + kk * 32);
    }
#pragma unroll
    for (int tl = 0; tl < 2; ++tl) {
        const unsigned short* srh = wcomb + (long)((4 + tl) * 1024 + jbase + col) * 1024 + kbase + quad * 8;
#pragma unroll
        for (int kk = 0; kk < 8; ++kk) wh[tl][kk] = *(const short8*)(srh + kk * 32);
        const unsigned short* srl = wreclo + (long)(tl * 1024 + jbase + col) * 1024 + kbase + quad * 8;
#pragma unroll
        for (int kk = 0; kk < 8; ++kk)
            *(short8*)&wlo[wv][tl][kk][lane * 8] = *(const short8*)(srl + kk * 32);
    }

    const int b_ = tid >> 4, j_ = tid & 15;
    // per-thread fp32 c for all 4 groups (static-indexed via x4 unroll)
    float cr0 = c0[(0 * 16 + b_) * 1024 + jbase + j_];
    float cr1 = c0[(1 * 16 + b_) * 1024 + jbase + j_];
    float cr2 = c0[(2 * 16 + b_) * 1024 + jbase + j_];
    float cr3 = c0[(3 * 16 + b_) * 1024 + jbase + j_];
    const int l0 = lengths[0 * 16 + b_], l1 = lengths[16 + b_];
    const int l2 = lengths[32 + b_],     l3 = lengths[48 + b_];

    // double-buffered state fragments (this wave's K-slice)
    short8 shA[8], scA[8], slA[8], shB[8], scB[8], slB[8];
    {   // prologue prefetch: slot 0 (g0, t0, read-parity 1)
        const int sb = 65536 + col * 1024 + kbase + quad * 8;
#pragma unroll
        for (int kk = 0; kk < 8; ++kk) {
            shA[kk] = ld_state(hst + sb + kk * 32);
            scA[kk] = ld_state(cst + sb + kk * 32);
            slA[kk] = ld_state(cstlo + sb + kk * 32);
        }
    }
    int fpre = 0;
    __syncthreads();

    float* out_h = out;
    float* out_c = out + 12320768;

#define SLOT(G_, CR_, LEN_, SH_C, SC_C, SL_C, SH_N, SC_N, SL_N)                               \
    {                                                                                          \
        const int sl = s + (G_);                                                               \
        const int b0 = (G_) * 16;                                                              \
        const int ps = (G_) & 1;                                                               \
        f4 pxa, pxb;                                                                           \
        if (wv == 0) {                                                                         \
            pxa = px_init(px, t, 0, jbase + col, b0 + quad * 4);                               \
            pxb = px_init(px, t, 1, jbase + col, b0 + quad * 4);                               \
        } else if (wv == 1) {                                                                  \
            pxa = px_init(px, t, 2, jbase + col, b0 + quad * 4);                               \
            pxb = px_init(px, t, 3, jbase + col, b0 + quad * 4);                               \
        }                                                                                      \
        f4 ag0 = {0.f, 0.f, 0.f, 0.f}, ag1 = ag0, ag2 = ag0, ag3 = ag0;                        \
        f4 ap0 = ag0, ap1 = ag0, ap2 = ag0, ap3 = ag0, ap4 = ag0, ap5 = ag0;                   \
        _Pragma("unroll")                                                                      \
        for (int kk = 0; kk < 8; ++kk) {                                                       \
            short8 lw0 = *(const short8*)&wlo[wv][0][kk][lane * 8];                            \
            short8 lw1 = *(const short8*)&wlo[wv][1][kk][lane * 8];                            \
            ag0 = MFMA(SH_C[kk], wg[0][kk], ag0);                                              \
            ag1 = MFMA(SH_C[kk], wg[1][kk], ag1);                                              \
            ag2 = MFMA(SH_C[kk], wg[2][kk], ag2);                                              \
            ag3 = MFMA(SH_C[kk], wg[3][kk], ag3);                                              \
            ap0 = MFMA(SC_C[kk], wh[0][kk], ap0);                                              \
            ap1 = MFMA(SC_C[kk], wh[1][kk], ap1);                                              \
            ap2 = MFMA(SL_C[kk], wh[0][kk], ap2);                                              \
            ap3 = MFMA(SL_C[kk], wh[1][kk], ap3);                                              \
            ap4 = MFMA(SC_C[kk], lw0, ap4);                                                    \
            ap5 = MFMA(SC_C[kk], lw1, ap5);                                                    \
        }                                                                                      \
        if (wv == 0) {                                                                         \
            _Pragma("unroll")                                                                  \
            for (int r = 0; r < 4; ++r) { ag0[r] += pxa[r]; ag1[r] += pxb[r]; }                \
        } else if (wv == 1) {                                                                  \
            _Pragma("unroll")                                                                  \
            for (int r = 0; r < 4; ++r) { ag2[r] += pxa[r]; ag3[r] += pxb[r]; }                \
        }                                                                                      \
        _Pragma("unroll")                                                                      \
        for (int r = 0; r < 4; ++r) {                                                          \
            pre[ps][wv][0][quad * 4 + r][col] = ag0[r];                                        \
            pre[ps][wv][1][quad * 4 + r][col] = ag1[r];                                        \
            pre[ps][wv][2][quad * 4 + r][col] = ag2[r];                                        \
            pre[ps][wv][3][quad * 4 + r][col] = ag3[r];                                        \
            pre[ps][wv][4][quad * 4 + r][col] = ap0[r] + ap2[r] + ap4[r];                      \
            pre[ps][wv][5][quad * 4 + r][col] = ap1[r] + ap3[r] + ap5[r];                      \
        }                                                                                      \
        if (sl >= 3 && sl + 1 < NSLOT) {                                                       \
            const int tn = (sl + 1) >> 2, gn = (sl + 1) & 3;                                   \
            if (!__all(fpre >= tn)) {                                                          \
                const int* fp = flags + gn * 64 + lane;                                        \
                for (;;) {                                                                     \
                    int a = __hip_atomic_load(fp, __ATOMIC_RELAXED, __HIP_MEMORY_SCOPE_AGENT); \
                    if (__all(a >= tn)) break;                                                 \
                    __builtin_amdgcn_s_sleep(1);                                               \
                }                                                                              \
            }                                                                                  \
        }                                                                                      \
        asm volatile("s_waitcnt vmcnt(0)" ::: "memory");                                       \
        if (sl + 1 < NSLOT) {                                                                  \
            const int tn = (sl + 1) >> 2, gn = (sl + 1) & 3;                                   \
            const int sb = ((tn + 1) & 1) * 65536 + (gn * 16 + col) * 1024 + kbase + quad * 8; \
            _Pragma("unroll")                                                                  \
            for (int kk = 0; kk < 8; ++kk) {                                                   \
                SH_N[kk] = ld_state(hst + sb + kk * 32);                                       \
                SC_N[kk] = ld_state(cst + sb + kk * 32);                                       \
                SL_N[kk] = ld_state(cstlo + sb + kk * 32);                                     \
            }                                                                                  \
        }                                                                                      \
        fpre = __hip_atomic_load(flags + (((G_) + 2) & 3) * 64 + lane, __ATOMIC_RELAXED,       \
                                 __HIP_MEMORY_SCOPE_AGENT);                                    \
        __syncthreads();                                                                       \
        asm volatile("" ::: "memory");                                                         \
        if (sl >= 1 && tid == 0)                                                               \
            __hip_atomic_store(&flags[((sl - 1) & 3) * 64 + cu], ((sl - 1) >> 2) + 1,          \
                               __ATOMIC_RELAXED, __HIP_MEMORY_SCOPE_AGENT);                    \
        {                                                                                      \
            float pi = 0.f, pf = 0.f, pg = 0.f, po = 0.f;                                      \
            _Pragma("unroll")                                                                  \
            for (int q = 0; q < 4; ++q) {                                                      \
                pi += pre[ps][q][0][b_][j_] + pre[ps][q][4][b_][j_];                           \
                pf += pre[ps][q][1][b_][j_] + pre[ps][q][5][b_][j_];                           \
                pg += pre[ps][q][2][b_][j_];                                                   \
                po += pre[ps][q][3][b_][j_];                                                   \
            }                                                                                  \
            const float cprev = CR_;                                                           \
            const float iv = sigf(pi), fv = sigf(pf), gv = tanh_(pg);                          \
            float cn = fv * cprev + iv * gv;                                                   \
            float ov = sigf(po + cn);                                                          \
            float hn = ov * tanh_(cn);                                                         \
            if (t >= (LEN_)) { hn = 0.f; cn = 0.f; }                                           \
            CR_ = cn;                                                                          \
            const long ob = (long)(b0 + b_) * 192512 + (long)t * 1024 + jbase + j_;            \
            const int sidx = (t & 1) * 65536 + (b0 + b_) * 1024 + jbase + j_;                  \
            unsigned short hb = f2b(hn), chb = f2b(cn), clb = f2b(cn - b2f(chb));              \
            __hip_atomic_store(&hst[sidx], hb, __ATOMIC_RELAXED, __HIP_MEMORY_SCOPE_AGENT);    \
            __hip_atomic_store(&cst[sidx], chb, __ATOMIC_RELAXED, __HIP_MEMORY_SCOPE_AGENT);   \
            __hip_atomic_store(&cstlo[sidx], clb, __ATOMIC_RELAXED, __HIP_MEMORY_SCOPE_AGENT); \
            out_h[ob] = hn;                                                                    \
            out_c[ob] = cn;                                                                    \
        }                                                                                      \
    }

    for (int s = 0; s < NSLOT; s += 4) {
        const int t = s >> 2;
        SLOT(0, cr0, l0, shA, scA, slA, shB, scB, slB)
        SLOT(1, cr1, l1, shB, scB, slB, shA, scA, slA)
        SLOT(2, cr2, l2, shA, scA, slA, shB, scB, slB)
        SLOT(3, cr3, l3, shB, scB, slB, shA, scA, slA)
    }
#undef SLOT
}

// ---------------------------------------------------------------------------
extern "C" void kernel_launch(void* const* d_in, const int* in_sizes, int n_in,
                              void* d_out, int out_size, void* d_ws, size_t ws_size,
                              hipStream_t stream) {
    const float* x    = (const float*)d_in[0];
    const float* h0   = (const float*)d_in[1];
    const float* c0   = (const float*)d_in[2];
    const float* wih  = (const float*)d_in[3];
    const float* whh  = (const float*)d_in[4];
    const float* wrec = (const float*)d_in[5];
    const float* bias = (const float*)d_in[6];
    const int* lengths = (const int*)d_in[7];

    char* ws = (char*)d_ws;
    unsigned short* px     = (unsigned short*)(ws + WS_PX);
    unsigned short* xb     = (unsigned short*)(ws + WS_XB);
    unsigned short* wihb   = (unsigned short*)(ws + WS_WIHB);
    unsigned short* wcomb  = (unsigned short*)(ws + WS_WCOMB);
    unsigned short* hst    = (unsigned short*)(ws + WS_HST);
    unsigned short* cst    = (unsigned short*)(ws + WS_CST);
    unsigned short* wreclo = (unsigned short*)(ws + WS_WRECLO);
    unsigned short* cstlo  = (unsigned short*)(ws + WS_CSTLO);
    int* flags             = (int*)(ws + WS_FLAGS);
    float* out = (float*)d_out;

    hipLaunchKernelGGL(k_prep, dim3(2048), dim3(256), 0, stream,
                       x, h0, c0, wih, whh, wrec, xb, wihb, wcomb, hst, cst, wreclo, cstlo, flags);
    hipLaunchKernelGGL(k_px, dim3(64, 188), dim3(256), 0, stream, xb, wihb, bias, px);
    hipLaunchKernelGGL(k_scan, dim3(64), dim3(256), 0, stream,
                       wcomb, wreclo, c0, lengths, px, hst, cst, cstlo, flags, out);
}

// Round 2
// 1666.382 us; speedup vs baseline: 3.2880x; 3.2880x over previous
//
#include <hip/hip_runtime.h>

// ---------------------------------------------------------------------------
// XiRNN (peephole LSTM) on MI355X.  B=64, T=188, I=512, H=R=1024.
//   k_prep : fp32->bf16 conversion; W_rec split into bf16 hi+lo; zero flags.
//   k_px   : px[t][gate][j][b] = x[b,t,:]·W_ih[gate*H+j,:] + bias (MFMA GEMM)
//   k_scan : persistent kernel, 256 blocks (1/CU), 4 batch-groups of 16 rows
//            x 64 CUs. Weights register-resident (AGPRs). Peephole in
//            compensated bf16. c kept fp32 in LDS locally; cross-CU state bf16.
//   R4: removed __threadfence: 56->16.8us/step.  R7: px-seed fix (0.289 bug).
//   R8 FAILED (4926us): time-multiplexing 4 groups on 64 CUs has NO latency
//   advantage (slot_time >= L/G, step = G*slot >= L, same as R7) and its
//   register appetite (~460 operand regs) blew the 512 unified file -> scratch
//   spills every slot (VGPR 256 cap, MfmaUtil 2%).
//   R9: back to R7 skeleton; attack L itself. R7's missing ~3600cy/step was
//   the state gather: 8B monotonic-atomic loads interleaved with consuming
//   MFMAs -> limited hoisting -> ~4-6 serialized L3 RTs. Now: batch ALL state
//   loads as 16B inline-asm sc0 sc1 loads (device-coherent, 1 instr each),
//   ONE s_waitcnt vmcnt(0) + sched_barrier(0) (guide rule #18), then MFMAs
//   from registers. ts1 gets 6 independent accumulators (was 2x3 dependent).
// ---------------------------------------------------------------------------

#define T_N 188

// ws byte offsets (256-aligned). Total = 132,648,960 B (~126.5 MiB).
#define WS_PX     0UL           // ushort[188*4096*64]   = 98,566,144 B
#define WS_XB     98566144UL    // ushort[64*188*512]    = 12,320,768 B
#define WS_WIHB   110886912UL   // ushort[4096*512]      =  4,194,304 B
#define WS_WCOMB  115081216UL   // ushort[6144*1024]     = 12,582,912 B
#define WS_HST    127664128UL   // ushort[2][64][1024]   =    262,144 B
#define WS_CST    127926272UL   // ushort[2][64][1024]   =    262,144 B
#define WS_FLAGS  128188416UL   // int[1024]             =      4,096 B
#define WS_WRECLO 128192512UL   // ushort[2048*1024]     =  4,194,304 B
#define WS_CSTLO  132386816UL   // ushort[2][64][1024]   =    262,144 B

typedef __attribute__((ext_vector_type(8))) short short8;
typedef __attribute__((ext_vector_type(4))) float f4;

__device__ __forceinline__ float b2f(unsigned short u) {
    union { unsigned int i; float f; } v; v.i = ((unsigned int)u) << 16; return v.f;
}
__device__ __forceinline__ unsigned short f2b(float f) {
    unsigned int u = __float_as_uint(f);
    return (unsigned short)((u + 0x7FFFu + ((u >> 16) & 1u)) >> 16);
}
__device__ __forceinline__ float sigf(float x) { return 1.0f / (1.0f + __expf(-x)); }
__device__ __forceinline__ float tanh_(float x) {
    float e = __expf(2.0f * x); return 1.0f - 2.0f / (e + 1.0f);
}
#define MFMA(a, b, c) __builtin_amdgcn_mfma_f32_16x16x32_bf16((a), (b), (c), 0, 0, 0)

// 16B device-coherent load (bypass L1/L2, served by L3). NOTE: result is NOT
// tracked by the compiler's waitcnt logic — caller must s_waitcnt vmcnt(0)
// + sched_barrier(0) before consuming (batched below).
#define LD16(dst, addr) \
    asm volatile("global_load_dwordx4 %0, %1, off sc0 sc1" : "=&v"(dst) : "v"(addr))

__device__ __forceinline__ f4 px_init(const unsigned short* px, int t, int gate, int jg, int brow) {
    unsigned long long pv =
        *(const unsigned long long*)(px + ((long)(t * 4 + gate) * 1024 + jg) * 64 + brow);
    f4 r;
    r[0] = b2f((unsigned short)pv);
    r[1] = b2f((unsigned short)(pv >> 16));
    r[2] = b2f((unsigned short)(pv >> 32));
    r[3] = b2f((unsigned short)(pv >> 48));
    return r;
}

// ---------------------------------------------------------------------------
__global__ void k_prep(const float* __restrict__ x, const float* __restrict__ h0,
                       const float* __restrict__ c0, const float* __restrict__ wih,
                       const float* __restrict__ whh, const float* __restrict__ wrec,
                       unsigned short* __restrict__ xb, unsigned short* __restrict__ wihb,
                       unsigned short* __restrict__ wcomb, unsigned short* __restrict__ hst,
                       unsigned short* __restrict__ cst, unsigned short* __restrict__ wreclo,
                       unsigned short* __restrict__ cstlo, int* __restrict__ flags) {
    const long NX4 = 1540096, NWIH4 = 524288, NWHH4 = 1048576, NWREC4 = 524288, NH4 = 16384;
    const long total = NX4 + NWIH4 + NWHH4 + NWREC4 + NH4 + NH4;
    long gtid = (long)blockIdx.x * blockDim.x + threadIdx.x;
    for (long i = gtid; i < total; i += (long)gridDim.x * blockDim.x) {
        const float* src; unsigned short* dst; unsigned short* lo_dst = nullptr; long off = i;
        if (off < NX4)                   { src = x;    dst = xb; }
        else if ((off -= NX4) < NWIH4)   { src = wih;  dst = wihb; }
        else if ((off -= NWIH4) < NWHH4) { src = whh;  dst = wcomb; }
        else if ((off -= NWHH4) < NWREC4){ src = wrec; dst = wcomb + 4194304; lo_dst = wreclo; }
        else if ((off -= NWREC4) < NH4)  { src = h0;   dst = hst + 65536; }     // state slot 1
        else { off -= NH4;                 src = c0;   dst = cst + 65536; lo_dst = cstlo + 65536; }
        float4 v = ((const float4*)src)[off];
        unsigned short hx = f2b(v.x), hy = f2b(v.y), hz = f2b(v.z), hw = f2b(v.w);
        unsigned long long o = (unsigned long long)hx
            | ((unsigned long long)hy << 16)
            | ((unsigned long long)hz << 32)
            | ((unsigned long long)hw << 48);
        *(unsigned long long*)(dst + off * 4) = o;
        if (lo_dst) {
            unsigned long long l = (unsigned long long)f2b(v.x - b2f(hx))
                | ((unsigned long long)f2b(v.y - b2f(hy)) << 16)
                | ((unsigned long long)f2b(v.z - b2f(hz)) << 32)
                | ((unsigned long long)f2b(v.w - b2f(hw)) << 48);
            *(unsigned long long*)(lo_dst + off * 4) = l;
        }
    }
    if (gtid < 1024) flags[gtid] = 0;
}

// ---------------------------------------------------------------------------
// px GEMM: block = (t, 64-col slab), 4 waves, each wave one 16-col tile, M=64.
__global__ void __launch_bounds__(256) k_px(const unsigned short* __restrict__ xb,
                                            const unsigned short* __restrict__ wihb,
                                            const float* __restrict__ bias,
                                            unsigned short* __restrict__ px) {
    const int t = blockIdx.y;
    const int wv = threadIdx.x >> 6, lane = threadIdx.x & 63;
    const int col = lane & 15, quad = lane >> 4;
    const int n = blockIdx.x * 64 + wv * 16 + col;   // 0..4095 combined gate*H+j
    const float bn = bias[n];
    f4 acc[4];
#pragma unroll
    for (int mt = 0; mt < 4; ++mt) { acc[mt][0] = bn; acc[mt][1] = bn; acc[mt][2] = bn; acc[mt][3] = bn; }
    const unsigned short* bp = wihb + n * 512 + quad * 8;
#pragma unroll 4
    for (int kk = 0; kk < 16; ++kk) {
        short8 bf = *(const short8*)(bp + kk * 32);
#pragma unroll
        for (int mt = 0; mt < 4; ++mt) {
            const unsigned short* ap = xb + ((mt * 16 + col) * 188 + t) * 512 + kk * 32 + quad * 8;
            short8 af = *(const short8*)ap;
            acc[mt] = MFMA(af, bf, acc[mt]);
        }
    }
    const long pb = ((long)(t * 4 + (n >> 10)) * 1024 + (n & 1023)) * 64;
#pragma unroll
    for (int mt = 0; mt < 4; ++mt) {
        unsigned long long o = (unsigned long long)f2b(acc[mt][0])
            | ((unsigned long long)f2b(acc[mt][1]) << 16)
            | ((unsigned long long)f2b(acc[mt][2]) << 32)
            | ((unsigned long long)f2b(acc[mt][3]) << 48);
        *(unsigned long long*)(px + pb + mt * 16 + quad * 4) = o;
    }
}

// ---------------------------------------------------------------------------
// Persistent scan. cu = blockIdx: group g = cu>>6 (16 batch rows), cig = cu&63
// (16 hidden indices). 4 waves: kh = wv>>1 (K-half), ts = wv&1.
//   ts0: tiles {i,f,g,o}, A = h (bf16), px gates 0..3 seeded at kh==0.
//   ts1: tiles {ri,rf} compensated (c_hi@W_hi + c_hi@W_lo + c_lo@W_hi),
//        seeded ZERO — peephole tiles carry no px term.
// R9: state gather = batched 16B sc0 sc1 loads -> regs -> one vmcnt(0) ->
//     sched_barrier(0) -> MFMAs. One L3 round trip instead of ~4-6.
__global__ void __launch_bounds__(256, 1) k_scan(
    const unsigned short* __restrict__ wcomb, const unsigned short* __restrict__ wreclo,
    const float* __restrict__ c0, const int* __restrict__ lengths,
    const unsigned short* __restrict__ px, unsigned short* __restrict__ hst,
    unsigned short* __restrict__ cst, unsigned short* __restrict__ cstlo,
    int* __restrict__ flags, float* __restrict__ out) {
    const int cu = blockIdx.x;
    const int g = cu >> 6, cig = cu & 63;
    const int jbase = cig * 16, b0 = g * 16;
    const int tid = threadIdx.x, wv = tid >> 6, lane = tid & 63;
    const int kh = wv >> 1, ts = wv & 1;
    const int kbase = kh * 512;
    const int col = lane & 15, quad = lane >> 4;

    __shared__ float pre[2][2][6][16][16];   // [slot][kh][tile][b][j]  24 KB
    __shared__ float c_loc[16][16];          // fp32 local c (never rounded)

    // One-time: weights -> regs (4 tiles x 16 k-chunks x 16B/lane)
    short8 wf[4][16];
#pragma unroll
    for (int tile = 0; tile < 4; ++tile) {
        // ts0: rows {0,1,2,3}*1024 (i,f,g,o from W_hh).
        // ts1: wf[0]=ri_hi (row 4096+), wf[1]=rf_hi (row 5120+),
        //      wf[2]=ri_lo, wf[3]=rf_lo (from wreclo rows 0/1024).
        const unsigned short* src;
        if (ts == 0) {
            src = wcomb + (long)(tile * 1024 + jbase + col) * 1024 + kbase + quad * 8;
        } else if (tile < 2) {
            src = wcomb + (long)((4 + tile) * 1024 + jbase + col) * 1024 + kbase + quad * 8;
        } else {
            src = wreclo + (long)((tile - 2) * 1024 + jbase + col) * 1024 + kbase + quad * 8;
        }
#pragma unroll
        for (int kk = 0; kk < 16; ++kk) wf[tile][kk] = *(const short8*)(src + kk * 32);
    }
    {
        int b = tid >> 4, j = tid & 15;
        c_loc[b][j] = c0[(b0 + b) * 1024 + jbase + j];
    }
    const int my_len = lengths[b0 + (tid >> 4)];
    __syncthreads();

    float* out_h = out;
    float* out_c = out + 12320768;

    for (int t = 0; t < T_N; ++t) {
        const int sl_r = (t + 1) & 1, sl_w = t & 1, ps = t & 1;

        // px loads (ts0/kh0 only — gates 0..3) are state-independent: issue
        // before the wait so they're in flight while we poll.
        f4 pxv[4];
        if (ts == 0 && kh == 0) {
#pragma unroll
            for (int tile = 0; tile < 4; ++tile)
                pxv[tile] = px_init(px, t, tile, jbase + col, b0 + quad * 4);
        }

        if (t > 0) {
            // Only wave 0 polls (lane i watches CU i of this group): 64
            // agent-scope transactions per iteration per CU.
            if (wv == 0) {
                const int* fp = flags + g * 64 + lane;
                for (;;) {
                    int a = __hip_atomic_load(fp, __ATOMIC_RELAXED, __HIP_MEMORY_SCOPE_AGENT);
                    if (__all(a >= t)) break;
                    __builtin_amdgcn_s_sleep(1);
                }
            }
            __syncthreads();   // release whole block once wave 0 saw all flags
            asm volatile("" ::: "memory");
        }

        const int sbase = sl_r * 65536 + (b0 + col) * 1024 + kbase + quad * 8;

        if (ts == 0) {
            const unsigned short* hp = hst + sbase;
            // Batch the entire h gather: 16 x 16B loads in flight at once.
            short8 hbuf[16];
#pragma unroll
            for (int kk = 0; kk < 16; ++kk) LD16(hbuf[kk], hp + kk * 32);
            f4 acc[4];
#pragma unroll
            for (int tile = 0; tile < 4; ++tile) {
                if (kh == 0) acc[tile] = pxv[tile];
                else { acc[tile][0] = 0.f; acc[tile][1] = 0.f; acc[tile][2] = 0.f; acc[tile][3] = 0.f; }
            }
            asm volatile("s_waitcnt vmcnt(0)" ::: "memory");
            __builtin_amdgcn_sched_barrier(0);
#pragma unroll
            for (int kk = 0; kk < 16; ++kk) {
                acc[0] = MFMA(hbuf[kk], wf[0][kk], acc[0]);
                acc[1] = MFMA(hbuf[kk], wf[1][kk], acc[1]);
                acc[2] = MFMA(hbuf[kk], wf[2][kk], acc[2]);
                acc[3] = MFMA(hbuf[kk], wf[3][kk], acc[3]);
            }
#pragma unroll
            for (int tile = 0; tile < 4; ++tile)
#pragma unroll
                for (int r = 0; r < 4; ++r) pre[ps][kh][tile][quad * 4 + r][col] = acc[tile][r];
        } else {
            const unsigned short* cph = cst + sbase;
            const unsigned short* cpl = cstlo + sbase;
            // Batch the entire c_hi + c_lo gather: 32 x 16B loads in flight.
            short8 chb[16], clb[16];
#pragma unroll
            for (int kk = 0; kk < 16; ++kk) LD16(chb[kk], cph + kk * 32);
#pragma unroll
            for (int kk = 0; kk < 16; ++kk) LD16(clb[kk], cpl + kk * 32);
            // 6 independent accumulator chains (was 2 chains of 3 dependent).
            f4 a0 = {0.f, 0.f, 0.f, 0.f}, a1 = a0, a2 = a0, a3 = a0, a4 = a0, a5 = a0;
            asm volatile("s_waitcnt vmcnt(0)" ::: "memory");
            __builtin_amdgcn_sched_barrier(0);
#pragma unroll
            for (int kk = 0; kk < 16; ++kk) {
                a0 = MFMA(chb[kk], wf[0][kk], a0);   // c_hi @ ri_hi
                a1 = MFMA(chb[kk], wf[1][kk], a1);   // c_hi @ rf_hi
                a2 = MFMA(chb[kk], wf[2][kk], a2);   // c_hi @ ri_lo
                a3 = MFMA(chb[kk], wf[3][kk], a3);   // c_hi @ rf_lo
                a4 = MFMA(clb[kk], wf[0][kk], a4);   // c_lo @ ri_hi
                a5 = MFMA(clb[kk], wf[1][kk], a5);   // c_lo @ rf_hi
            }
#pragma unroll
            for (int r = 0; r < 4; ++r) {
                pre[ps][kh][4][quad * 4 + r][col] = a0[r] + a2[r] + a4[r];
                pre[ps][kh][5][quad * 4 + r][col] = a1[r] + a3[r] + a5[r];
            }
        }
        __syncthreads();

        float hn, cn; long ob;
        {
            const int b = tid >> 4, j = tid & 15;
            float pi = pre[ps][0][0][b][j] + pre[ps][1][0][b][j] + pre[ps][0][4][b][j] + pre[ps][1][4][b][j];
            float pf = pre[ps][0][1][b][j] + pre[ps][1][1][b][j] + pre[ps][0][5][b][j] + pre[ps][1][5][b][j];
            float pg = pre[ps][0][2][b][j] + pre[ps][1][2][b][j];
            float po = pre[ps][0][3][b][j] + pre[ps][1][3][b][j];
            const float cprev = c_loc[b][j];
            const float iv = sigf(pi), fv = sigf(pf), gv = tanh_(pg);
            cn = fv * cprev + iv * gv;
            float ov = sigf(po + cn);
            hn = ov * tanh_(cn);
            if (t >= my_len) { hn = 0.f; cn = 0.f; }
            c_loc[b][j] = cn;
            ob = (long)(b0 + b) * 192512 + (long)t * 1024 + jbase + j;
            const int sidx = sl_w * 65536 + (b0 + b) * 1024 + jbase + j;
            unsigned short hb  = f2b(hn);
            unsigned short chb2 = f2b(cn);
            unsigned short clb2 = f2b(cn - b2f(chb2));
            __hip_atomic_store(&hst[sidx],  hb,   __ATOMIC_RELAXED, __HIP_MEMORY_SCOPE_AGENT);
            __hip_atomic_store(&cst[sidx],  chb2, __ATOMIC_RELAXED, __HIP_MEMORY_SCOPE_AGENT);
            __hip_atomic_store(&cstlo[sidx], clb2, __ATOMIC_RELAXED, __HIP_MEMORY_SCOPE_AGENT);
        }
        // Release: each wave drains its own state stores, barrier so all
        // waves' stores are complete, then ONE flag per CU.
        asm volatile("s_waitcnt vmcnt(0)" ::: "memory");
        __syncthreads();
        if (tid == 0)
            __hip_atomic_store(&flags[cu], t + 1, __ATOMIC_RELAXED, __HIP_MEMORY_SCOPE_AGENT);
        // Out stores AFTER the flag post: not consumed by other CUs, so they
        // stay off the critical path (drained by next step's vmcnt(0)).
        out_h[ob] = hn;
        out_c[ob] = cn;
    }
}

// ---------------------------------------------------------------------------
extern "C" void kernel_launch(void* const* d_in, const int* in_sizes, int n_in,
                              void* d_out, int out_size, void* d_ws, size_t ws_size,
                              hipStream_t stream) {
    const float* x    = (const float*)d_in[0];
    const float* h0   = (const float*)d_in[1];
    const float* c0   = (const float*)d_in[2];
    const float* wih  = (const float*)d_in[3];
    const float* whh  = (const float*)d_in[4];
    const float* wrec = (const float*)d_in[5];
    const float* bias = (const float*)d_in[6];
    const int* lengths = (const int*)d_in[7];

    char* ws = (char*)d_ws;
    unsigned short* px     = (unsigned short*)(ws + WS_PX);
    unsigned short* xb     = (unsigned short*)(ws + WS_XB);
    unsigned short* wihb   = (unsigned short*)(ws + WS_WIHB);
    unsigned short* wcomb  = (unsigned short*)(ws + WS_WCOMB);
    unsigned short* hst    = (unsigned short*)(ws + WS_HST);
    unsigned short* cst    = (unsigned short*)(ws + WS_CST);
    unsigned short* wreclo = (unsigned short*)(ws + WS_WRECLO);
    unsigned short* cstlo  = (unsigned short*)(ws + WS_CSTLO);
    int* flags             = (int*)(ws + WS_FLAGS);
    float* out = (float*)d_out;

    hipLaunchKernelGGL(k_prep, dim3(2048), dim3(256), 0, stream,
                       x, h0, c0, wih, whh, wrec, xb, wihb, wcomb, hst, cst, wreclo, cstlo, flags);
    hipLaunchKernelGGL(k_px, dim3(64, 188), dim3(256), 0, stream, xb, wihb, bias, px);
    hipLaunchKernelGGL(k_scan, dim3(256), dim3(256), 0, stream,
                       wcomb, wreclo, c0, lengths, px, hst, cst, cstlo, flags, out);
}